// Round 16
// baseline (32.257 us; speedup 1.0000x reference)
//
#include <hip/hip_runtime.h>
#include <math.h>

#define H_BINS 61
#define HB2 (H_BINS * H_BINS)       // 3721
#define SLOTS (3 * HB2)             // 11163
#define NPIX 22500                  // 150*150
#define NIMG 64
#define OUT_ELEMS (NIMG * SLOTS)

#define REP 2                       // LDS replicas (29.8KB)
#define NCH 5                       // chunks per (img,pair): grid 960 = ~4 blocks/CU
#define PPC (NPIX / NCH)            // 4500 pixels per chunk
#define NT 512                      // 8 waves/block (proven shape)
#define PSTRIDE 3728                // padded partial stride (u32 words)
#define NPART (NIMG * 3 * NCH)      // 960 partials

#define EPSF 2.2204e-16f
#define HALFW ((float)(6.4 / 61.0 / 2.0))
#define FXSCALE 1048576.0f          // 2^20 fixed-point scale
#define FXINV   (1.0f / 1048576.0f)

// A[h] = -3.2f + h*delta, all f32 rn ops (mirrors linspace in f32; rn blocks FMA)
__device__ __forceinline__ float bin_center(int h) {
    const float delta = __fdiv_rn(__fsub_rn(3.0951f, -3.2f), 60.0f);
    return __fadd_rn(-3.2f, __fmul_rn((float)h, delta));
}

// Exact-predicate bin lookup, 2 candidates, branchless, array-free (R7/R8).
__device__ __forceinline__ int find_bin(float t) {
    const float inv_delta = 60.0f / 6.2951f;   // estimate only
    int k = (int)floorf(__fmul_rn(__fadd_rn(t, 3.2f), inv_delta));
    int best = -1;
    #pragma unroll
    for (int dh = 0; dh <= 1; ++dh) {
        int h = k + dh;
        bool in_rng = ((unsigned)h < (unsigned)H_BINS);
        bool hit = (fabsf(__fsub_rn(t, bin_center(h))) <= HALFW);
        best = (in_rng && hit) ? h : best;
    }
    return best;
}

// R14 structure (proven 28.6us), single change: NCH 4 -> 5 (768 -> 960 blocks,
// ~4 blocks/CU = 32 waves/CU, all co-resident). One block = (image,pair,chunk);
// u32 fixed-point ds_add; 2 LDS replicas (lane&1).
__global__ __launch_bounds__(NT) void hist_rep(const float* __restrict__ X,
                                               unsigned* __restrict__ partials) {
    __shared__ unsigned hist[REP * HB2];       // 29,768 B
    const int bid = blockIdx.x;
    const int c   = bid % NCH;
    const int bp  = bid / NCH;                 // (b*3 + p), pairs interleaved
    const int p   = bp % 3;
    const int b   = bp / 3;

    for (int i = threadIdx.x; i < REP * HB2; i += NT) hist[i] = 0u;
    __syncthreads();

    const float* Xb = X + (size_t)b * 3 * NPIX;
    const int n0 = c * PPC;
    const int n1 = n0 + PPC;
    unsigned* hrep = hist + (threadIdx.x & (REP - 1)) * HB2;

    for (int n = n0 + threadIdx.x; n < n1; n += NT) {
        float r  = Xb[n];
        float g  = Xb[NPIX + n];
        float bl = Xb[2 * NPIX + n];

        // identical per-pixel arithmetic to all passing rounds
        float iy = __fsqrt_rn(__fadd_rn(
            __fadd_rn(__fmul_rn(r, r), __fmul_rn(g, g)), __fmul_rn(bl, bl)));
        float l0 = logf(__fadd_rn(fabsf(r),  EPSF));
        float l1 = logf(__fadd_rn(fabsf(g),  EPSF));
        float l2 = logf(__fadd_rn(fabsf(bl), EPSF));

        float iu, iv;                          // wave-uniform branch (p per block)
        if (p == 0)      { iu = __fsub_rn(l0, l1); iv = __fsub_rn(l0, l2); }
        else if (p == 1) { iu = __fsub_rn(l1, l0); iv = __fsub_rn(l1, l2); }
        else             { iu = __fsub_rn(l2, l0); iv = __fsub_rn(l2, l1); }

        int u = find_bin(iu);
        int v = find_bin(iv);
        if (u >= 0 && v >= 0) {
            // fixed-point round-to-nearest; iy<=1.74 => q fits easily
            unsigned q = (unsigned)(__fmul_rn(iy, FXSCALE) + 0.5f);
            atomicAdd(hrep + (u * H_BINS + v), q);   // native ds_add_u32
        }
    }
    __syncthreads();

    // merge replicas (EXACT integer adds) + flush one partial
    unsigned* dst = partials + (size_t)bid * PSTRIDE;
    for (int j = threadIdx.x; j < HB2; j += NT)
        dst[j] = hist[j] + hist[HB2 + j];
}

// One block per (img,pair): sum 5 chunk-partials (exact u32), convert once,
// sqrt*C/N, write out.
__global__ __launch_bounds__(256) void reduce2(const unsigned* __restrict__ partials,
                                               const float* __restrict__ C,
                                               float* __restrict__ out) {
    const int bp = blockIdx.x;                 // (b*3 + p)
    const int p  = bp % 3;
    const int b  = bp / 3;
    float scale = __fdiv_rn(C[p], 22500.0f);   // C[i]/N in f32
    const unsigned* base = partials + (size_t)bp * NCH * PSTRIDE;
    float* ob = out + (size_t)b * SLOTS + p * HB2;
    for (int j = threadIdx.x; j < HB2; j += 256) {
        unsigned s = 0u;
        #pragma unroll
        for (int c = 0; c < NCH; ++c) s += base[(size_t)c * PSTRIDE + j];
        float h = __fmul_rn((float)s, FXINV);  // exact pow2 scale
        ob[j] = __fmul_rn(__fsqrt_rn(h), scale);
    }
}

// ---- tiny-ws fallback (not taken with 256MB ws): f32 LDS path (R8-proven) ----
#define DO_PAIR(P, IU, IV)                                                   \
    {                                                                        \
        int bu_ = find_bin(IU);                                              \
        int bv_ = find_bin(IV);                                              \
        if (bu_ >= 0 && bv_ >= 0)                                            \
            unsafeAtomicAdd(&hflat[(P) * HB2 + bu_ * H_BINS + bv_], iy);     \
    }
#define DO_PIXEL(r, g, bl)                                                   \
    {                                                                        \
        float iy = __fsqrt_rn(__fadd_rn(                                     \
            __fadd_rn(__fmul_rn(r, r), __fmul_rn(g, g)), __fmul_rn(bl, bl)));\
        float l0 = logf(__fadd_rn(fabsf(r),  EPSF));                         \
        float l1 = logf(__fadd_rn(fabsf(g),  EPSF));                         \
        float l2 = logf(__fadd_rn(fabsf(bl), EPSF));                         \
        DO_PAIR(0, __fsub_rn(l0, l1), __fsub_rn(l0, l2))                     \
        DO_PAIR(1, __fsub_rn(l1, l0), __fsub_rn(l1, l2))                     \
        DO_PAIR(2, __fsub_rn(l2, l0), __fsub_rn(l2, l1))                     \
    }
__global__ __launch_bounds__(256) void zero_out(float4* __restrict__ o, int n4) {
    int i = blockIdx.x * 256 + threadIdx.x;
    if (i < n4) o[i] = make_float4(0.f, 0.f, 0.f, 0.f);
}
__global__ __launch_bounds__(512) void hist_atomic(const float* __restrict__ X,
                                                   float* __restrict__ out) {
    __shared__ float hflat[SLOTS];
    const int chunk = blockIdx.x % 12;
    const int b     = blockIdx.x / 12;
    for (int i = threadIdx.x; i < SLOTS; i += 512) hflat[i] = 0.0f;
    __syncthreads();
    const float* Xb = X + (size_t)b * 3 * NPIX;
    const int ppc = NPIX / 12;
    for (int n = chunk * ppc + threadIdx.x; n < (chunk + 1) * ppc; n += 512) {
        float r = Xb[n], g = Xb[NPIX + n], bl = Xb[2 * NPIX + n];
        DO_PIXEL(r, g, bl)
    }
    __syncthreads();
    float* ob = out + (size_t)b * SLOTS;
    for (int i = threadIdx.x; i < SLOTS; i += 512) {
        float v = hflat[i];
        if (v != 0.0f) unsafeAtomicAdd(&ob[i], v);
    }
}
__global__ __launch_bounds__(256) void finalize_inplace(float* __restrict__ out,
                                                        const float* __restrict__ C) {
    int idx = blockIdx.x * 256 + threadIdx.x;
    if (idx >= OUT_ELEMS) return;
    int ch = (idx / HB2) % 3;
    float scale = __fdiv_rn(C[ch], 22500.0f);
    out[idx] = __fmul_rn(__fsqrt_rn(out[idx]), scale);
}

extern "C" void kernel_launch(void* const* d_in, const int* in_sizes, int n_in,
                              void* d_out, int out_size, void* d_ws, size_t ws_size,
                              hipStream_t stream) {
    const float* X = (const float*)d_in[0];
    const float* C = (const float*)d_in[1];
    float* out = (float*)d_out;

    const size_t need = (size_t)NPART * PSTRIDE * sizeof(unsigned);   // ~14.3 MB
    if (ws_size >= need) {
        unsigned* partials = (unsigned*)d_ws;
        hist_rep<<<NPART, NT, 0, stream>>>(X, partials);
        reduce2<<<NIMG * 3, 256, 0, stream>>>(partials, C, out);
    } else {
        int n4 = OUT_ELEMS / 4;
        zero_out<<<(n4 + 255) / 256, 256, 0, stream>>>((float4*)out, n4);
        hist_atomic<<<NIMG * 12, 512, 0, stream>>>(X, out);
        finalize_inplace<<<(OUT_ELEMS + 255) / 256, 256, 0, stream>>>(out, C);
    }
}

// Round 17
// 27.879 us; speedup vs baseline: 1.1570x; 1.1570x over previous
//
#include <hip/hip_runtime.h>
#include <math.h>

#define H_BINS 61
#define HB2 (H_BINS * H_BINS)       // 3721
#define HB2P 3724                   // replica stride, padded to 16B multiple
#define SLOTS (3 * HB2)             // 11163
#define NPIX 22500                  // 150*150
#define NIMG 64
#define OUT_ELEMS (NIMG * SLOTS)

#define REP 2                       // LDS replicas (29.8KB; 3 blocks/CU resident)
#define NCH 4                       // chunks per (img,pair) -> 768 blocks, 3/CU uniform
#define PPC (NPIX / NCH)            // 5625 pixels per chunk
#define NT 512                      // 8 waves/block (R14-proven shape)
#define PSTRIDE 3728                // padded partial stride (u32 words)
#define NPART (NIMG * 3 * NCH)      // 768 partials

#define EPSF 2.2204e-16f
#define HALFW ((float)(6.4 / 61.0 / 2.0))
#define FXSCALE 1048576.0f          // 2^20 fixed-point scale
#define FXINV   (1.0f / 1048576.0f)

// A[h] = -3.2f + h*delta, all f32 rn ops (mirrors linspace in f32; rn blocks FMA)
__device__ __forceinline__ float bin_center(int h) {
    const float delta = __fdiv_rn(__fsub_rn(3.0951f, -3.2f), 60.0f);
    return __fadd_rn(-3.2f, __fmul_rn((float)h, delta));
}

// Exact-predicate bin lookup, 2 candidates, branchless, array-free (R7/R8).
__device__ __forceinline__ int find_bin(float t) {
    const float inv_delta = 60.0f / 6.2951f;   // estimate only
    int k = (int)floorf(__fmul_rn(__fadd_rn(t, 3.2f), inv_delta));
    int best = -1;
    #pragma unroll
    for (int dh = 0; dh <= 1; ++dh) {
        int h = k + dh;
        bool in_rng = ((unsigned)h < (unsigned)H_BINS);
        bool hit = (fabsf(__fsub_rn(t, bin_center(h))) <= HALFW);
        best = (in_rng && hit) ? h : best;
    }
    return best;
}

// R14 structure EXACTLY (proven 28.6us): one block = (image, pair, chunk),
// bid interleaved (c = bid&3), u32 fixed-point ds_add, REP=2 (lane&1).
// Only change: 16B-aligned replica stride -> uint4 init & flush.
__global__ __launch_bounds__(NT) void hist_rep(const float* __restrict__ X,
                                               unsigned* __restrict__ partials) {
    __shared__ unsigned hist[REP * HB2P];      // 29,792 B -> 3 blocks/CU (LDS ok)
    const int bid = blockIdx.x;
    const int c   = bid & (NCH - 1);
    const int bp  = bid >> 2;                  // (b*3 + p), pairs interleaved
    const int p   = bp % 3;
    const int b   = bp / 3;

    {   // vectorized zero-init: 1862 uint4 stores
        uint4* h4 = (uint4*)hist;
        uint4 z = make_uint4(0u, 0u, 0u, 0u);
        for (int i = threadIdx.x; i < (REP * HB2P) / 4; i += NT) h4[i] = z;
    }
    __syncthreads();

    const float* Xb = X + (size_t)b * 3 * NPIX;
    const int n0 = c * PPC;
    const int n1 = n0 + PPC;
    unsigned* hrep = hist + (threadIdx.x & (REP - 1)) * HB2P;

    for (int n = n0 + threadIdx.x; n < n1; n += NT) {
        float r  = Xb[n];
        float g  = Xb[NPIX + n];
        float bl = Xb[2 * NPIX + n];

        // identical per-pixel arithmetic to all passing rounds
        float iy = __fsqrt_rn(__fadd_rn(
            __fadd_rn(__fmul_rn(r, r), __fmul_rn(g, g)), __fmul_rn(bl, bl)));
        float l0 = logf(__fadd_rn(fabsf(r),  EPSF));
        float l1 = logf(__fadd_rn(fabsf(g),  EPSF));
        float l2 = logf(__fadd_rn(fabsf(bl), EPSF));

        float iu, iv;                          // wave-uniform branch (p per block)
        if (p == 0)      { iu = __fsub_rn(l0, l1); iv = __fsub_rn(l0, l2); }
        else if (p == 1) { iu = __fsub_rn(l1, l0); iv = __fsub_rn(l1, l2); }
        else             { iu = __fsub_rn(l2, l0); iv = __fsub_rn(l2, l1); }

        int u = find_bin(iu);
        int v = find_bin(iv);
        if (u >= 0 && v >= 0) {
            // fixed-point round-to-nearest; iy<=1.74 => q fits easily
            unsigned q = (unsigned)(__fmul_rn(iy, FXSCALE) + 0.5f);
            atomicAdd(hrep + (u * H_BINS + v), q);   // native ds_add_u32
        }
    }
    __syncthreads();

    // merge replicas (EXACT integer adds) + flush, uint4-vectorized:
    // 931 uint4 = 3724 words (3721 real + 3 pad; PSTRIDE=3728 has room)
    {
        const uint4* h4a = (const uint4*)hist;
        const uint4* h4b = (const uint4*)(hist + HB2P);
        uint4* dst4 = (uint4*)(partials + (size_t)bid * PSTRIDE);
        for (int i = threadIdx.x; i < HB2P / 4; i += NT) {
            uint4 a = h4a[i], bb = h4b[i];
            a.x += bb.x; a.y += bb.y; a.z += bb.z; a.w += bb.w;
            dst4[i] = a;
        }
    }
}

// One block per (img,pair): sum 4 chunk-partials (exact u32), convert once,
// sqrt*C/N, write out. (unchanged from R14)
__global__ __launch_bounds__(256) void reduce2(const unsigned* __restrict__ partials,
                                               const float* __restrict__ C,
                                               float* __restrict__ out) {
    const int bp = blockIdx.x;                 // (b*3 + p)
    const int p  = bp % 3;
    const int b  = bp / 3;
    float scale = __fdiv_rn(C[p], 22500.0f);   // C[i]/N in f32
    const unsigned* base = partials + (size_t)bp * NCH * PSTRIDE;
    float* ob = out + (size_t)b * SLOTS + p * HB2;
    for (int j = threadIdx.x; j < HB2; j += 256) {
        unsigned s = base[j] + base[PSTRIDE + j]
                   + base[2 * PSTRIDE + j] + base[3 * PSTRIDE + j];
        float h = __fmul_rn((float)s, FXINV);  // exact pow2 scale
        ob[j] = __fmul_rn(__fsqrt_rn(h), scale);
    }
}

// ---- tiny-ws fallback (not taken with 256MB ws): f32 LDS path (R8-proven) ----
#define DO_PAIR(P, IU, IV)                                                   \
    {                                                                        \
        int bu_ = find_bin(IU);                                              \
        int bv_ = find_bin(IV);                                              \
        if (bu_ >= 0 && bv_ >= 0)                                            \
            unsafeAtomicAdd(&hflat[(P) * HB2 + bu_ * H_BINS + bv_], iy);     \
    }
#define DO_PIXEL(r, g, bl)                                                   \
    {                                                                        \
        float iy = __fsqrt_rn(__fadd_rn(                                     \
            __fadd_rn(__fmul_rn(r, r), __fmul_rn(g, g)), __fmul_rn(bl, bl)));\
        float l0 = logf(__fadd_rn(fabsf(r),  EPSF));                         \
        float l1 = logf(__fadd_rn(fabsf(g),  EPSF));                         \
        float l2 = logf(__fadd_rn(fabsf(bl), EPSF));                         \
        DO_PAIR(0, __fsub_rn(l0, l1), __fsub_rn(l0, l2))                     \
        DO_PAIR(1, __fsub_rn(l1, l0), __fsub_rn(l1, l2))                     \
        DO_PAIR(2, __fsub_rn(l2, l0), __fsub_rn(l2, l1))                     \
    }
__global__ __launch_bounds__(256) void zero_out(float4* __restrict__ o, int n4) {
    int i = blockIdx.x * 256 + threadIdx.x;
    if (i < n4) o[i] = make_float4(0.f, 0.f, 0.f, 0.f);
}
__global__ __launch_bounds__(512) void hist_atomic(const float* __restrict__ X,
                                                   float* __restrict__ out) {
    __shared__ float hflat[SLOTS];
    const int chunk = blockIdx.x % 12;
    const int b     = blockIdx.x / 12;
    for (int i = threadIdx.x; i < SLOTS; i += 512) hflat[i] = 0.0f;
    __syncthreads();
    const float* Xb = X + (size_t)b * 3 * NPIX;
    const int ppc = NPIX / 12;
    for (int n = chunk * ppc + threadIdx.x; n < (chunk + 1) * ppc; n += 512) {
        float r = Xb[n], g = Xb[NPIX + n], bl = Xb[2 * NPIX + n];
        DO_PIXEL(r, g, bl)
    }
    __syncthreads();
    float* ob = out + (size_t)b * SLOTS;
    for (int i = threadIdx.x; i < SLOTS; i += 512) {
        float v = hflat[i];
        if (v != 0.0f) unsafeAtomicAdd(&ob[i], v);
    }
}
__global__ __launch_bounds__(256) void finalize_inplace(float* __restrict__ out,
                                                        const float* __restrict__ C) {
    int idx = blockIdx.x * 256 + threadIdx.x;
    if (idx >= OUT_ELEMS) return;
    int ch = (idx / HB2) % 3;
    float scale = __fdiv_rn(C[ch], 22500.0f);
    out[idx] = __fmul_rn(__fsqrt_rn(out[idx]), scale);
}

extern "C" void kernel_launch(void* const* d_in, const int* in_sizes, int n_in,
                              void* d_out, int out_size, void* d_ws, size_t ws_size,
                              hipStream_t stream) {
    const float* X = (const float*)d_in[0];
    const float* C = (const float*)d_in[1];
    float* out = (float*)d_out;

    const size_t need = (size_t)NPART * PSTRIDE * sizeof(unsigned);   // ~11.4 MB
    if (ws_size >= need) {
        unsigned* partials = (unsigned*)d_ws;
        hist_rep<<<NPART, NT, 0, stream>>>(X, partials);
        reduce2<<<NIMG * 3, 256, 0, stream>>>(partials, C, out);
    } else {
        int n4 = OUT_ELEMS / 4;
        zero_out<<<(n4 + 255) / 256, 256, 0, stream>>>((float4*)out, n4);
        hist_atomic<<<NIMG * 12, 512, 0, stream>>>(X, out);
        finalize_inplace<<<(OUT_ELEMS + 255) / 256, 256, 0, stream>>>(out, C);
    }
}